// Round 10
// baseline (161.675 us; speedup 1.0000x reference)
//
#include <hip/hip_runtime.h>

typedef __attribute__((ext_vector_type(4)))  float    f32x4;
typedef __attribute__((ext_vector_type(16))) float    f32x16;
typedef __attribute__((ext_vector_type(8)))  _Float16 half8;
typedef __attribute__((ext_vector_type(2)))  __fp16   fp16x2;
typedef __attribute__((ext_vector_type(4)))  _Float16 half4;
typedef __attribute__((ext_vector_type(8)))  short    short8;

#define SCL2E 0.18033688011112042f   // (1/8) * log2(e)  — folded into Q

__device__ __forceinline__ unsigned short f2h_bits(float x) {
    union { _Float16 h; unsigned short u; } c;
    c.h = (_Float16)x;
    return c.u;
}

// ============ prepass (fused, UNCHANGED from r9): K and V^T -> f16 FRAGMENT-MAJOR ============
// ws[bh][tile(32)][slot(8)][lane(64)][j(8)]  (8 KB per 64-kv tile)
__global__ __launch_bounds__(256)
void cvt_kv_kernel(const float* __restrict__ K, const float* __restrict__ V,
                   unsigned short* __restrict__ wsK, unsigned short* __restrict__ wsV) {
    int bid = blockIdx.x;                           // 0..8191
    if (bid < 4096) {
        int t   = bid * 256 + threadIdx.x;
        int eg  = t & 15;
        int gr  = t >> 4;
        int kv  = gr & 2047, bh = gr >> 11;
        int b = bh >> 3, h = bh & 7;
        const float* sp = K + (((size_t)b * 2048 + kv) * 8 + h) * 64 + eg * 4;
        f32x4 v = *(const f32x4*)sp;
        int T    = kv >> 6;
        int kh   = (kv >> 5) & 1;
        int ks   = eg >> 2;
        int hi   = eg & 1;
        int lane = (kv & 31) + 32 * hi;
        int joff = 4 * ((eg >> 1) & 1);
        size_t idx = (((size_t)bh * 32 + T) * 4096) + ((kh * 4 + ks) * 64 + lane) * 8 + joff;
        union { unsigned short s[4]; unsigned long long u; } o;
        o.s[0] = f2h_bits(v[0]); o.s[1] = f2h_bits(v[1]);
        o.s[2] = f2h_bits(v[2]); o.s[3] = f2h_bits(v[3]);
        *(unsigned long long*)(wsK + idx) = o.u;
    } else {
        int t   = (bid - 4096) * 256 + threadIdx.x;
        int d   = t & 63;
        int g   = t >> 6;
        int kv4 = g & 511, bh = g >> 9;
        int b = bh >> 3, h = bh & 7;
        int kv = kv4 * 4;
        const float* sp = V + (((size_t)b * 2048 + kv) * 8 + h) * 64 + d;
        float v0 = sp[0], v1 = sp[512], v2 = sp[1024], v3 = sp[1536];
        int T    = kv >> 6;
        int kvt  = kv & 63;
        int kh   = kvt >> 5;
        int kvh  = kvt & 31;
        int kc   = kvh >> 4;
        int hi   = (kvh >> 2) & 1;
        int joff = 4 * ((kvh >> 3) & 1);
        int dh   = d >> 5;
        int lane = (d & 31) + 32 * hi;
        size_t idx = (((size_t)bh * 32 + T) * 4096) + ((kh * 4 + dh * 2 + kc) * 64 + lane) * 8 + joff;
        union { unsigned short s[4]; unsigned long long u; } o;
        o.s[0] = f2h_bits(v0); o.s[1] = f2h_bits(v1);
        o.s[2] = f2h_bits(v2); o.s[3] = f2h_bits(v3);
        *(unsigned long long*)(wsV + idx) = o.u;
    }
}

// ---------------- main v10: staggered waves + reg-dbuf K prefetch + split chains ----------------
#define LOADK4(D0, D1, D2, D3, TT) {                                              \
    const unsigned short* _kp = Ksrc + (size_t)(TT) * 4096;                       \
    D0 = *(const half8*)&_kp[lane * 8];                                           \
    D1 = *(const half8*)&_kp[512 + lane * 8];                                     \
    D2 = *(const half8*)&_kp[1024 + lane * 8];                                    \
    D3 = *(const half8*)&_kp[1536 + lane * 8]; }

#define BODY(KC0, KC1, KC2, KC3, KN0, KN1, KN2, KN3, TPF, TV) {                   \
    LOADK4(KN0, KN1, KN2, KN3, TPF);                                              \
    const unsigned short* _vp = Vsrc + (size_t)(TV) * 4096;                       \
    half8 vf00 = *(const half8*)&_vp[lane * 8];                                   \
    half8 vf01 = *(const half8*)&_vp[512 + lane * 8];                             \
    half8 vf10 = *(const half8*)&_vp[1024 + lane * 8];                            \
    half8 vf11 = *(const half8*)&_vp[1536 + lane * 8];                            \
    f32x16 sA = Zv, sB = Zv;                                                      \
    __builtin_amdgcn_s_setprio(1);                                                \
    sA = __builtin_amdgcn_mfma_f32_32x32x16_f16(KC0, qf[0], sA, 0, 0, 0);         \
    sB = __builtin_amdgcn_mfma_f32_32x32x16_f16(KC1, qf[1], sB, 0, 0, 0);         \
    sA = __builtin_amdgcn_mfma_f32_32x32x16_f16(KC2, qf[2], sA, 0, 0, 0);         \
    sB = __builtin_amdgcn_mfma_f32_32x32x16_f16(KC3, qf[3], sB, 0, 0, 0);         \
    __builtin_amdgcn_s_setprio(0);                                                \
    half8 pf0, pf1;                                                               \
    float pSa = 0.f, pSb = 0.f;                                                   \
    { union { fp16x2 h2[4]; half8 v; } _u;                                        \
      _Pragma("unroll")                                                           \
      for (int j = 0; j < 4; ++j) {                                               \
          float _e0 = __builtin_amdgcn_exp2f(sA[2*j]     + sB[2*j]);              \
          float _e1 = __builtin_amdgcn_exp2f(sA[2*j + 1] + sB[2*j + 1]);          \
          _u.h2[j] = __builtin_amdgcn_cvt_pkrtz(_e0, _e1);                        \
          pSa = __builtin_amdgcn_fdot2(_u.h2[j], vone, pSa, false);               \
      }                                                                           \
      pf0 = _u.v; }                                                               \
    { union { fp16x2 h2[4]; half8 v; } _u;                                        \
      _Pragma("unroll")                                                           \
      for (int j = 0; j < 4; ++j) {                                               \
          float _e0 = __builtin_amdgcn_exp2f(sA[8 + 2*j]     + sB[8 + 2*j]);      \
          float _e1 = __builtin_amdgcn_exp2f(sA[8 + 2*j + 1] + sB[8 + 2*j + 1]);  \
          _u.h2[j] = __builtin_amdgcn_cvt_pkrtz(_e0, _e1);                        \
          pSb = __builtin_amdgcn_fdot2(_u.h2[j], vone, pSb, false);               \
      }                                                                           \
      pf1 = _u.v; }                                                               \
    lrow += pSa + pSb;                                                            \
    __builtin_amdgcn_s_setprio(1);                                                \
    acc0 = __builtin_amdgcn_mfma_f32_32x32x16_f16(vf00, pf0, acc0, 0, 0, 0);      \
    acc1 = __builtin_amdgcn_mfma_f32_32x32x16_f16(vf10, pf0, acc1, 0, 0, 0);      \
    acc0 = __builtin_amdgcn_mfma_f32_32x32x16_f16(vf01, pf1, acc0, 0, 0, 0);      \
    acc1 = __builtin_amdgcn_mfma_f32_32x32x16_f16(vf11, pf1, acc1, 0, 0, 0);      \
    __builtin_amdgcn_s_setprio(0);                                                \
}

__global__ __launch_bounds__(256, 4)
void attn_v10_kernel(const float* __restrict__ Q,
                     const unsigned short* __restrict__ wsK,
                     const unsigned short* __restrict__ wsV,
                     float* __restrict__ O) {
    __shared__ __align__(16) float mlds[4608];   // merge buffer only

    const int tid  = threadIdx.x;
    const int lane = tid & 63;
    const int w    = tid >> 6;          // wave 0..3
    const int qw   = w & 1;             // q chunk (32 rows)
    const int kh   = w >> 1;            // kv half
    const int lq   = lane & 31;
    const int hi   = lane >> 5;

    const int bid = blockIdx.x;
    const int xcd = bid & 7, slot = bid >> 3;
    const int qt  = slot & 31;
    const int bh  = ((slot >> 5) << 3) | xcd;    // XCD-local bh
    const int q0  = qt * 64;
    const int b   = bh >> 3, h = bh & 7;

    const unsigned short* Ksrc = wsK + (size_t)bh * 32 * 4096 + kh * 2048;
    const unsigned short* Vsrc = wsV + (size_t)bh * 32 * 4096 + kh * 2048;
    float* Og = O + ((size_t)b * 2048 * 8 + (size_t)h) * 64;

    // ---- Q fragments in registers (v8-verified mapping) ----
    half8 qf[4];
    {
        const float* qp = Q + (((size_t)b * 2048 + q0 + qw * 32 + lq) * 8 + h) * 64;
#pragma unroll
        for (int ks = 0; ks < 4; ++ks) {
            f32x4 a = *(const f32x4*)(qp + 16 * ks + 4 * hi);
            f32x4 c = *(const f32x4*)(qp + 16 * ks + 8 + 4 * hi);
            union { fp16x2 h2[4]; half8 v; } u;
            u.h2[0] = __builtin_amdgcn_cvt_pkrtz(a[0] * SCL2E, a[1] * SCL2E);
            u.h2[1] = __builtin_amdgcn_cvt_pkrtz(a[2] * SCL2E, a[3] * SCL2E);
            u.h2[2] = __builtin_amdgcn_cvt_pkrtz(c[0] * SCL2E, c[1] * SCL2E);
            u.h2[3] = __builtin_amdgcn_cvt_pkrtz(c[2] * SCL2E, c[3] * SCL2E);
            qf[ks] = u.v;
        }
    }

    const f32x16 Zv = {0.f,0.f,0.f,0.f,0.f,0.f,0.f,0.f,0.f,0.f,0.f,0.f,0.f,0.f,0.f,0.f};
    f32x16 acc0 = Zv, acc1 = Zv;
    float lrow = 0.f;
    const fp16x2 vone = {(__fp16)1.0f, (__fp16)1.0f};

    // stagger start tile per wave (and mildly per block) — sums are order-invariant
    const int t0 = (w * 8 + (slot & 3) * 2) & 31;

    half8 kA0, kA1, kA2, kA3, kB0, kB1, kB2, kB3;
    LOADK4(kA0, kA1, kA2, kA3, t0);

    int tcur = t0;
    for (int u = 0; u < 32; u += 2) {
        const int tn1 = (tcur + 1) & 31;
        const int tn2 = (tcur + 2) & 31;
        BODY(kA0, kA1, kA2, kA3, kB0, kB1, kB2, kB3, tn1, tcur);   // compute tcur, prefetch tn1
        BODY(kB0, kB1, kB2, kB3, kA0, kA1, kA2, kA3, tn2, tn1);    // compute tn1, prefetch tn2
        tcur = tn2;
    }

    // ---- epilogue: merge lane halves of l, then merge kv halves via LDS (v9-verified) ----
    lrow += __shfl_xor(lrow, 32);

    const int mslot = (qw * 64 + lane) * 36;
    if (kh) {
        float* dst = mlds + mslot;
#pragma unroll
        for (int a = 0; a < 4; ++a) {
            *(f32x4*)(dst + 4 * a)      = (f32x4){acc0[4*a], acc0[4*a+1], acc0[4*a+2], acc0[4*a+3]};
            *(f32x4*)(dst + 16 + 4 * a) = (f32x4){acc1[4*a], acc1[4*a+1], acc1[4*a+2], acc1[4*a+3]};
        }
        dst[32] = lrow;
    }
    __syncthreads();
    if (!kh) {
        const float* src = mlds + mslot;
        float inv = 1.0f / (lrow + src[32]);

        const int qg = q0 + qw * 32 + lq;
        float* orow = Og + (size_t)qg * 512;
#pragma unroll
        for (int a = 0; a < 4; ++a) {
            f32x4 p0 = *(const f32x4*)(src + 4 * a);
            f32x4 p1 = *(const f32x4*)(src + 16 + 4 * a);
            f32x4 o0, o1;
#pragma unroll
            for (int i = 0; i < 4; ++i) {
                o0[i] = (acc0[4 * a + i] + p0[i]) * inv;
                o1[i] = (acc1[4 * a + i] + p1[i]) * inv;
            }
            *(f32x4*)(orow + 8 * a + 4 * hi)      = o0;
            *(f32x4*)(orow + 32 + 8 * a + 4 * hi) = o1;
        }
    }
}

// ================= fallback (round-1 kernel, passes) =================
__device__ __forceinline__ unsigned short f2bf(float f) {
    union { float f; unsigned u; } v; v.f = f;
    unsigned u = v.u;
    u += 0x7fffu + ((u >> 16) & 1u);
    return (unsigned short)(u >> 16);
}

__global__ __launch_bounds__(128, 2)
void attn_v1_kernel(const float* __restrict__ Q, const float* __restrict__ K,
                    const float* __restrict__ V, float* __restrict__ O) {
    __shared__ __align__(16) unsigned short lds_q[64 * 64];
    __shared__ __align__(16) unsigned short lds_k[64 * 64];
    __shared__ __align__(16) unsigned short lds_v[64 * 64];

    const int tid = threadIdx.x, lane = tid & 63, wv = tid >> 6;
    const int lq = lane & 15, g = lane >> 4;
    const int bid = blockIdx.x, xcd = bid & 7, slot = bid >> 3;
    const int qt = slot & 31;
    const int bh = ((slot >> 5) << 3) | xcd;
    const int b = bh >> 3, h = bh & 7;
    const size_t base = ((size_t)b * 2048 * 8 + (size_t)h) * 64;
    const float* Qg = Q + base; const float* Kg = K + base;
    const float* Vg = V + base; float* Og = O + base;
    const int q0 = qt * 64;
    const float S2E = 0.125f * 1.44269504088896341f;

#pragma unroll
    for (int p = 0; p < 16; ++p) {
        int r = (tid >> 5) + p * 4, e = (tid & 31) * 2;
        const float* src = Qg + (size_t)(q0 + r) * 512 + e;
        unsigned pk = (unsigned)f2bf(src[0]) | ((unsigned)f2bf(src[1]) << 16);
        *(unsigned*)&lds_q[(r * 64 + e) ^ ((r & 7) << 3)] = pk;
    }
    __syncthreads();
    short8 qf[2][2];
#pragma unroll
    for (int qc = 0; qc < 2; ++qc) {
        int row = wv * 32 + qc * 16 + lq;
#pragma unroll
        for (int j = 0; j < 2; ++j)
            qf[qc][j] = *(const short8*)&lds_q[(row * 64 + j * 32 + g * 8) ^ ((row & 7) << 3)];
    }
    f32x4 acc[2][4];
#pragma unroll
    for (int qc = 0; qc < 2; ++qc)
#pragma unroll
        for (int dc = 0; dc < 4; ++dc) acc[qc][dc] = (f32x4){0.f, 0.f, 0.f, 0.f};
    float mrow[2] = {-1e30f, -1e30f}, lrow[2] = {0.f, 0.f};

    for (int t = 0; t < 32; ++t) {
        const int kv0 = t * 64;
        __syncthreads();
#pragma unroll
        for (int p = 0; p < 16; ++p) {
            int r = (tid >> 5) + p * 4, e = (tid & 31) * 2;
            const float* src = Kg + (size_t)(kv0 + r) * 512 + e;
            unsigned pk = (unsigned)f2bf(src[0]) | ((unsigned)f2bf(src[1]) << 16);
            *(unsigned*)&lds_k[(r * 64 + e) ^ ((r & 7) << 3)] = pk;
        }
#pragma unroll
        for (int p = 0; p < 16; ++p) {
            int d = tid & 63, kv = (p * 2 + (tid >> 6)) * 2;
            float v0 = Vg[(size_t)(kv0 + kv) * 512 + d];
            float v1 = Vg[(size_t)(kv0 + kv + 1) * 512 + d];
            union { _Float16 hh[2]; unsigned u; } pk;
            pk.hh[0] = (_Float16)v0; pk.hh[1] = (_Float16)v1;
            *(unsigned*)&lds_v[(d * 64 + kv) ^ ((d & 15) << 2)] = pk.u;
        }
        __syncthreads();
        f32x4 sfr[2][4];
#pragma unroll
        for (int kc = 0; kc < 4; ++kc) {
            int row = kc * 16 + lq;
            short8 kf0 = *(const short8*)&lds_k[(row * 64 + 0 + g * 8) ^ ((row & 7) << 3)];
            short8 kf1 = *(const short8*)&lds_k[(row * 64 + 32 + g * 8) ^ ((row & 7) << 3)];
#pragma unroll
            for (int qc = 0; qc < 2; ++qc) {
                f32x4 sx = __builtin_amdgcn_mfma_f32_16x16x32_bf16(kf0, qf[qc][0], (f32x4){0.f,0.f,0.f,0.f}, 0, 0, 0);
                sx = __builtin_amdgcn_mfma_f32_16x16x32_bf16(kf1, qf[qc][1], sx, 0, 0, 0);
                sfr[qc][kc] = sx;
            }
        }
        half4 pfv[2][4];
#pragma unroll
        for (int qc = 0; qc < 2; ++qc) {
            float smax = -1e30f;
#pragma unroll
            for (int kc = 0; kc < 4; ++kc)
#pragma unroll
                for (int r = 0; r < 4; ++r) smax = fmaxf(smax, sfr[qc][kc][r]);
            smax = fmaxf(smax, __shfl_xor(smax, 16));
            smax = fmaxf(smax, __shfl_xor(smax, 32));
            float mn = fmaxf(mrow[qc], smax);
            float alpha = __builtin_amdgcn_exp2f((mrow[qc] - mn) * S2E);
            mrow[qc] = mn;
            float msc = mn * S2E, psum = 0.f;
#pragma unroll
            for (int kc = 0; kc < 4; ++kc)
#pragma unroll
                for (int r = 0; r < 4; ++r) {
                    float p = __builtin_amdgcn_exp2f(sfr[qc][kc][r] * S2E - msc);
                    psum += p;
                    pfv[qc][kc][r] = (_Float16)p;
                }
            psum += __shfl_xor(psum, 16);
            psum += __shfl_xor(psum, 32);
            lrow[qc] = lrow[qc] * alpha + psum;
#pragma unroll
            for (int dc = 0; dc < 4; ++dc) acc[qc][dc] *= alpha;
        }
#pragma unroll
        for (int dc = 0; dc < 4; ++dc) {
            int dd = dc * 16 + lq;
#pragma unroll
            for (int kc = 0; kc < 4; ++kc) {
                half4 vf = *(const half4*)&lds_v[(dd * 64 + kc * 16 + g * 4) ^ ((dd & 15) << 2)];
                acc[0][dc] = __builtin_amdgcn_mfma_f32_16x16x16f16(vf, pfv[0][kc], acc[0][dc], 0, 0, 0);
                acc[1][dc] = __builtin_amdgcn_mfma_f32_16x16x16f16(vf, pfv[1][kc], acc[1][dc], 0, 0, 0);
            }
        }
    }
#pragma unroll
    for (int qc = 0; qc < 2; ++qc) {
        float inv = 1.f / lrow[qc];
        int qrow = q0 + wv * 32 + qc * 16 + lq;
#pragma unroll
        for (int dc = 0; dc < 4; ++dc) {
            f32x4 o = acc[qc][dc] * inv;
            *(f32x4*)(Og + (size_t)qrow * 512 + dc * 16 + g * 4) = o;
        }
    }
}

extern "C" void kernel_launch(void* const* d_in, const int* in_sizes, int n_in,
                              void* d_out, int out_size, void* d_ws, size_t ws_size,
                              hipStream_t stream) {
    const float* Q = (const float*)d_in[0];
    const float* K = (const float*)d_in[1];
    const float* V = (const float*)d_in[2];
    float* O = (float*)d_out;

    const size_t per = (size_t)32 * 2048 * 64;            // elements per tensor
    const size_t need = 2 * per * sizeof(unsigned short); // 16 MB (K + V only)
    if (ws_size >= need) {
        unsigned short* wsK = (unsigned short*)d_ws;
        unsigned short* wsV = wsK + per;
        cvt_kv_kernel<<<dim3(8192), dim3(256), 0, stream>>>(K, V, wsK, wsV);
        attn_v10_kernel<<<dim3(1024), dim3(256), 0, stream>>>(Q, wsK, wsV, O);
    } else {
        attn_v1_kernel<<<dim3(1024), dim3(128), 0, stream>>>(Q, K, V, O);
    }
}

// Round 11
// 81.819 us; speedup vs baseline: 1.9760x; 1.9760x over previous
//
#include <hip/hip_runtime.h>

typedef __attribute__((ext_vector_type(4)))  float    f32x4;
typedef __attribute__((ext_vector_type(16))) float    f32x16;
typedef __attribute__((ext_vector_type(8)))  _Float16 half8;
typedef __attribute__((ext_vector_type(2)))  __fp16   fp16x2;
typedef __attribute__((ext_vector_type(4)))  _Float16 half4;
typedef __attribute__((ext_vector_type(8)))  short    short8;

#define SCL2E 0.18033688011112042f   // (1/8) * log2(e)  — folded into Q

__device__ __forceinline__ unsigned short f2h_bits(float x) {
    union { _Float16 h; unsigned short u; } c;
    c.h = (_Float16)x;
    return c.u;
}

__device__ __forceinline__ void gl_lds16(const unsigned short* g, unsigned short* l) {
    __builtin_amdgcn_global_load_lds((const __attribute__((address_space(1))) void*)g,
                                     (__attribute__((address_space(3))) void*)l, 16, 0, 0);
}

// ============ prepass (fused): K -> [bh][tile][32][128] granule-swizzled (r7-verified),
//                              V -> fragment-major [bh][tile][slot][lane][8] (r9-verified) ============
__global__ __launch_bounds__(256)
void cvt_kv_kernel(const float* __restrict__ K, const float* __restrict__ V,
                   unsigned short* __restrict__ wsK, unsigned short* __restrict__ wsV) {
    int bid = blockIdx.x;                           // 0..8191
    if (bid < 4096) {
        // K: [b][kv][h][e] -> granule layout (verified r7)
        int t   = bid * 256 + threadIdx.x;
        int eg  = t & 15;                           // e = eg*4
        int gr  = t >> 4;
        int kv  = gr & 2047, bh = gr >> 11;
        int b = bh >> 3, h = bh & 7;
        const float* sp = K + (((size_t)b * 2048 + kv) * 8 + h) * 64 + eg * 4;
        f32x4 v = *(const f32x4*)sp;
        int T = kv >> 6, R = kv & 31, half = (kv >> 5) & 1;
        int egp = (eg & ~3) | ((eg & 1) << 1) | ((eg >> 1) & 1);   // swap e bits 2,3
        int gnl = (half * 8 + (egp >> 1)) ^ (R & 15);
        size_t idx = (((size_t)bh * 32 + T) * 32 + R) * 128 + gnl * 8 + (egp & 1) * 4;
        union { unsigned short s[4]; unsigned long long u; } o;
        o.s[0] = f2h_bits(v[0]); o.s[1] = f2h_bits(v[1]);
        o.s[2] = f2h_bits(v[2]); o.s[3] = f2h_bits(v[3]);
        *(unsigned long long*)(wsK + idx) = o.u;
    } else {
        // V: fragment-major (verified r9): slot = kvh32*4 + dh*2 + kc
        int t   = (bid - 4096) * 256 + threadIdx.x;
        int d   = t & 63;
        int g   = t >> 6;
        int kv4 = g & 511, bh = g >> 9;
        int b = bh >> 3, h = bh & 7;
        int kv = kv4 * 4;
        const float* sp = V + (((size_t)b * 2048 + kv) * 8 + h) * 64 + d;
        float v0 = sp[0], v1 = sp[512], v2 = sp[1024], v3 = sp[1536];
        int T    = kv >> 6;
        int kvt  = kv & 63;
        int kh   = kvt >> 5;                 // kv half within tile
        int kvh  = kvt & 31;
        int kc   = kvh >> 4;
        int hi   = (kvh >> 2) & 1;
        int joff = 4 * ((kvh >> 3) & 1);
        int dh   = d >> 5;
        int lane = (d & 31) + 32 * hi;
        size_t idx = (((size_t)bh * 32 + T) * 4096) + ((kh * 4 + dh * 2 + kc) * 64 + lane) * 8 + joff;
        union { unsigned short s[4]; unsigned long long u; } o;
        o.s[0] = f2h_bits(v0); o.s[1] = f2h_bits(v1);
        o.s[2] = f2h_bits(v2); o.s[3] = f2h_bits(v3);
        *(unsigned long long*)(wsV + idx) = o.u;
    }
}

// ---------------- main v11: K via LDS (DMA), V direct-global — split the fragment traffic ----------------
// 8 waves = 4 q-chunks x 2 kv-tile-ranges, QBLK=128, grid 512.
__global__ __launch_bounds__(512, 4)
void attn_v11_kernel(const float* __restrict__ Q,
                     const unsigned short* __restrict__ wsK,
                     const unsigned short* __restrict__ wsV,
                     float* __restrict__ O) {
    __shared__ __align__(16) unsigned char smem[36864];   // 32KB K-dbuf, reused as 36KB merge
    unsigned short* kl = (unsigned short*)smem;           // [buf][kh][4096]

    const int tid  = threadIdx.x;
    const int lane = tid & 63;
    const int w    = tid >> 6;          // wave 0..7
    const int qw   = w & 3;             // q chunk
    const int kh   = w >> 2;            // kv tile range (0..15 / 16..31)
    const int lq   = lane & 31;
    const int hi   = lane >> 5;

    const int bid = blockIdx.x;
    const int xcd = bid & 7, slot = bid >> 3;
    const int qt  = slot & 15;
    const int bh  = ((slot >> 4) << 3) | xcd;   // XCD-local bh
    const int q0  = qt * 128;
    const int b   = bh >> 3, h = bh & 7;

    const unsigned short* Ksrc = wsK + (size_t)bh * 32 * 4096;   // [tile][32][128]
    const unsigned short* Vsrc = wsV + (size_t)bh * 32 * 4096;   // [tile][slot][lane][8]
    float* Og = O + ((size_t)b * 2048 * 8 + (size_t)h) * 64;

    // ---- Q fragments in registers (v8-verified mapping; scale folded) ----
    half8 qf[4];
    {
        const float* qp = Q + (((size_t)b * 2048 + q0 + qw * 32 + lq) * 8 + h) * 64;
#pragma unroll
        for (int ks = 0; ks < 4; ++ks) {
            f32x4 a = *(const f32x4*)(qp + 16 * ks + 4 * hi);
            f32x4 c = *(const f32x4*)(qp + 16 * ks + 8 + 4 * hi);
            union { fp16x2 h2[4]; half8 v; } u;
            u.h2[0] = __builtin_amdgcn_cvt_pkrtz(a[0] * SCL2E, a[1] * SCL2E);
            u.h2[1] = __builtin_amdgcn_cvt_pkrtz(a[2] * SCL2E, a[3] * SCL2E);
            u.h2[2] = __builtin_amdgcn_cvt_pkrtz(c[0] * SCL2E, c[1] * SCL2E);
            u.h2[3] = __builtin_amdgcn_cvt_pkrtz(c[2] * SCL2E, c[3] * SCL2E);
            qf[ks] = u.v;
        }
    }

    // stage K tiles 0 and 16 into buf 0 (one 16B chunk per thread per tile)
    gl_lds16(Ksrc + (size_t)0  * 4096 + tid * 8, &kl[(0 * 2 + 0) * 4096 + tid * 8]);
    gl_lds16(Ksrc + (size_t)16 * 4096 + tid * 8, &kl[(0 * 2 + 1) * 4096 + tid * 8]);
    __syncthreads();

    // K fragment granule offsets (r7-verified, conflict-free)
    int of0[4], of1[4];
#pragma unroll
    for (int ks = 0; ks < 4; ++ks) {
        of0[ks] = (((ks * 2 + hi)     ^ (lq & 15)) << 3);   // kv rows 0..31 of tile
        of1[ks] = (((8 + ks * 2 + hi) ^ (lq & 15)) << 3);   // kv rows 32..63
    }

    f32x16 acc0 = {0.f,0.f,0.f,0.f,0.f,0.f,0.f,0.f,0.f,0.f,0.f,0.f,0.f,0.f,0.f,0.f};
    f32x16 acc1 = acc0;
    float lrowA = 0.f, lrowB = 0.f;
    const fp16x2 vone = {(__fp16)1.0f, (__fp16)1.0f};

    for (int t = 0; t < 16; ++t) {
        const int cur = t & 1;
        if (t + 1 < 16) {   // stage next K tile pair into other buffer
            const int nxt = cur ^ 1;
            gl_lds16(Ksrc + (size_t)(t + 1)  * 4096 + tid * 8, &kl[(nxt * 2 + 0) * 4096 + tid * 8]);
            gl_lds16(Ksrc + (size_t)(t + 17) * 4096 + tid * 8, &kl[(nxt * 2 + 1) * 4096 + tid * 8]);
        }

        // ---- V fragments for this wave's tile: 8 coalesced global b128 (issued early) ----
        const unsigned short* vp = Vsrc + (size_t)(kh * 16 + t) * 4096;
        half8 vf0 = *(const half8*)&vp[0 * 512 + lane * 8];   // hm0 dh0 kc0
        half8 vf1 = *(const half8*)&vp[1 * 512 + lane * 8];   // hm0 dh0 kc1
        half8 vf2 = *(const half8*)&vp[2 * 512 + lane * 8];   // hm0 dh1 kc0
        half8 vf3 = *(const half8*)&vp[3 * 512 + lane * 8];   // hm0 dh1 kc1
        half8 vf4 = *(const half8*)&vp[4 * 512 + lane * 8];   // hm1 dh0 kc0
        half8 vf5 = *(const half8*)&vp[5 * 512 + lane * 8];   // hm1 dh0 kc1
        half8 vf6 = *(const half8*)&vp[6 * 512 + lane * 8];   // hm1 dh1 kc0
        half8 vf7 = *(const half8*)&vp[7 * 512 + lane * 8];   // hm1 dh1 kc1

        // ---- S^T = K · Q^T from LDS ----
        const unsigned short* kb = &kl[(cur * 2 + kh) * 4096];
        f32x16 s0 = {0.f,0.f,0.f,0.f,0.f,0.f,0.f,0.f,0.f,0.f,0.f,0.f,0.f,0.f,0.f,0.f};
        f32x16 s1 = s0;
        __builtin_amdgcn_s_setprio(1);
#pragma unroll
        for (int ks = 0; ks < 4; ++ks) {
            half8 kf0 = *(const half8*)&kb[lq * 128 + of0[ks]];
            half8 kf1 = *(const half8*)&kb[lq * 128 + of1[ks]];
            s0 = __builtin_amdgcn_mfma_f32_32x32x16_f16(kf0, qf[ks], s0, 0, 0, 0);
            s1 = __builtin_amdgcn_mfma_f32_32x32x16_f16(kf1, qf[ks], s1, 0, 0, 0);
        }
        __builtin_amdgcn_s_setprio(0);

        // ---- p = exp2(s); pack to f16; psum via fdot2 (v6-verified) ----
        half8 pf[4];
        float pA = 0.f, pB = 0.f;
#pragma unroll
        for (int hm = 0; hm < 2; ++hm) {
            const f32x16& sb = hm ? s1 : s0;
#pragma unroll
            for (int hk = 0; hk < 2; ++hk) {
                union { fp16x2 h2[4]; half8 v; } u;
#pragma unroll
                for (int j = 0; j < 4; ++j) {
                    float e0 = __builtin_amdgcn_exp2f(sb[8 * hk + 2 * j]);
                    float e1 = __builtin_amdgcn_exp2f(sb[8 * hk + 2 * j + 1]);
                    u.h2[j] = __builtin_amdgcn_cvt_pkrtz(e0, e1);
#if __has_builtin(__builtin_amdgcn_fdot2)
                    if (hm == 0) pA = __builtin_amdgcn_fdot2(u.h2[j], vone, pA, false);
                    else         pB = __builtin_amdgcn_fdot2(u.h2[j], vone, pB, false);
#else
                    if (hm == 0) pA += e0 + e1; else pB += e0 + e1;
#endif
                }
                pf[2 * hm + hk] = u.v;
            }
        }
        lrowA += pA; lrowB += pB;

        // ---- O^T += V^T · P^T  (pf[2*hm+hk] x vf slot hm*4+dh*2+hk) ----
        __builtin_amdgcn_s_setprio(1);
        acc0 = __builtin_amdgcn_mfma_f32_32x32x16_f16(vf0, pf[0], acc0, 0, 0, 0);
        acc1 = __builtin_amdgcn_mfma_f32_32x32x16_f16(vf2, pf[0], acc1, 0, 0, 0);
        acc0 = __builtin_amdgcn_mfma_f32_32x32x16_f16(vf1, pf[1], acc0, 0, 0, 0);
        acc1 = __builtin_amdgcn_mfma_f32_32x32x16_f16(vf3, pf[1], acc1, 0, 0, 0);
        acc0 = __builtin_amdgcn_mfma_f32_32x32x16_f16(vf4, pf[2], acc0, 0, 0, 0);
        acc1 = __builtin_amdgcn_mfma_f32_32x32x16_f16(vf6, pf[2], acc1, 0, 0, 0);
        acc0 = __builtin_amdgcn_mfma_f32_32x32x16_f16(vf5, pf[3], acc0, 0, 0, 0);
        acc1 = __builtin_amdgcn_mfma_f32_32x32x16_f16(vf7, pf[3], acc1, 0, 0, 0);
        __builtin_amdgcn_s_setprio(0);

        __syncthreads();   // K stage(t+1) landed + all LDS reads of cur done
    }

    // ---- epilogue: merge lane halves of l, then merge kh halves via LDS (v6-verified) ----
    float lrow = lrowA + lrowB;
    lrow += __shfl_xor(lrow, 32);

    float* mlds = (float*)smem;   // 4*64*36*4 = 36,864 B
    const int mslot = (qw * 64 + lane) * 36;
    if (kh) {
        float* dst = mlds + mslot;
#pragma unroll
        for (int a = 0; a < 4; ++a) {
            *(f32x4*)(dst + 4 * a)      = (f32x4){acc0[4*a], acc0[4*a+1], acc0[4*a+2], acc0[4*a+3]};
            *(f32x4*)(dst + 16 + 4 * a) = (f32x4){acc1[4*a], acc1[4*a+1], acc1[4*a+2], acc1[4*a+3]};
        }
        dst[32] = lrow;
    }
    __syncthreads();
    if (!kh) {
        const float* src = mlds + mslot;
        float inv = 1.0f / (lrow + src[32]);

        const int qg = q0 + qw * 32 + lq;
        float* orow = Og + (size_t)qg * 512;
#pragma unroll
        for (int a = 0; a < 4; ++a) {
            f32x4 p0 = *(const f32x4*)(src + 4 * a);
            f32x4 p1 = *(const f32x4*)(src + 16 + 4 * a);
            f32x4 o0, o1;
#pragma unroll
            for (int i = 0; i < 4; ++i) {
                o0[i] = (acc0[4 * a + i] + p0[i]) * inv;
                o1[i] = (acc1[4 * a + i] + p1[i]) * inv;
            }
            *(f32x4*)(orow + 8 * a + 4 * hi)      = o0;
            *(f32x4*)(orow + 32 + 8 * a + 4 * hi) = o1;
        }
    }
}

// ================= fallback (round-1 kernel, passes) =================
__device__ __forceinline__ unsigned short f2bf(float f) {
    union { float f; unsigned u; } v; v.f = f;
    unsigned u = v.u;
    u += 0x7fffu + ((u >> 16) & 1u);
    return (unsigned short)(u >> 16);
}

__global__ __launch_bounds__(128, 2)
void attn_v1_kernel(const float* __restrict__ Q, const float* __restrict__ K,
                    const float* __restrict__ V, float* __restrict__ O) {
    __shared__ __align__(16) unsigned short lds_q[64 * 64];
    __shared__ __align__(16) unsigned short lds_k[64 * 64];
    __shared__ __align__(16) unsigned short lds_v[64 * 64];

    const int tid = threadIdx.x, lane = tid & 63, wv = tid >> 6;
    const int lq = lane & 15, g = lane >> 4;
    const int bid = blockIdx.x, xcd = bid & 7, slot = bid >> 3;
    const int qt = slot & 31;
    const int bh = ((slot >> 5) << 3) | xcd;
    const int b = bh >> 3, h = bh & 7;
    const size_t base = ((size_t)b * 2048 * 8 + (size_t)h) * 64;
    const float* Qg = Q + base; const float* Kg = K + base;
    const float* Vg = V + base; float* Og = O + base;
    const int q0 = qt * 64;
    const float S2E = 0.125f * 1.44269504088896341f;

#pragma unroll
    for (int p = 0; p < 16; ++p) {
        int r = (tid >> 5) + p * 4, e = (tid & 31) * 2;
        const float* src = Qg + (size_t)(q0 + r) * 512 + e;
        unsigned pk = (unsigned)f2bf(src[0]) | ((unsigned)f2bf(src[1]) << 16);
        *(unsigned*)&lds_q[(r * 64 + e) ^ ((r & 7) << 3)] = pk;
    }
    __syncthreads();
    short8 qf[2][2];
#pragma unroll
    for (int qc = 0; qc < 2; ++qc) {
        int row = wv * 32 + qc * 16 + lq;
#pragma unroll
        for (int j = 0; j < 2; ++j)
            qf[qc][j] = *(const short8*)&lds_q[(row * 64 + j * 32 + g * 8) ^ ((row & 7) << 3)];
    }
    f32x4 acc[2][4];
#pragma unroll
    for (int qc = 0; qc < 2; ++qc)
#pragma unroll
        for (int dc = 0; dc < 4; ++dc) acc[qc][dc] = (f32x4){0.f, 0.f, 0.f, 0.f};
    float mrow[2] = {-1e30f, -1e30f}, lrow[2] = {0.f, 0.f};

    for (int t = 0; t < 32; ++t) {
        const int kv0 = t * 64;
        __syncthreads();
#pragma unroll
        for (int p = 0; p < 16; ++p) {
            int r = (tid >> 5) + p * 4, e = (tid & 31) * 2;
            const float* src = Kg + (size_t)(kv0 + r) * 512 + e;
            unsigned pk = (unsigned)f2bf(src[0]) | ((unsigned)f2bf(src[1]) << 16);
            *(unsigned*)&lds_k[(r * 64 + e) ^ ((r & 7) << 3)] = pk;
        }
#pragma unroll
        for (int p = 0; p < 16; ++p) {
            int d = tid & 63, kv = (p * 2 + (tid >> 6)) * 2;
            float v0 = Vg[(size_t)(kv0 + kv) * 512 + d];
            float v1 = Vg[(size_t)(kv0 + kv + 1) * 512 + d];
            union { _Float16 hh[2]; unsigned u; } pk;
            pk.hh[0] = (_Float16)v0; pk.hh[1] = (_Float16)v1;
            *(unsigned*)&lds_v[(d * 64 + kv) ^ ((d & 15) << 2)] = pk.u;
        }
        __syncthreads();
        f32x4 sfr[2][4];
#pragma unroll
        for (int kc = 0; kc < 4; ++kc) {
            int row = kc * 16 + lq;
            short8 kf0 = *(const short8*)&lds_k[(row * 64 + 0 + g * 8) ^ ((row & 7) << 3)];
            short8 kf1 = *(const short8*)&lds_k[(row * 64 + 32 + g * 8) ^ ((row & 7) << 3)];
#pragma unroll
            for (int qc = 0; qc < 2; ++qc) {
                f32x4 sx = __builtin_amdgcn_mfma_f32_16x16x32_bf16(kf0, qf[qc][0], (f32x4){0.f,0.f,0.f,0.f}, 0, 0, 0);
                sx = __builtin_amdgcn_mfma_f32_16x16x32_bf16(kf1, qf[qc][1], sx, 0, 0, 0);
                sfr[qc][kc] = sx;
            }
        }
        half4 pfv[2][4];
#pragma unroll
        for (int qc = 0; qc < 2; ++qc) {
            float smax = -1e30f;
#pragma unroll
            for (int kc = 0; kc < 4; ++kc)
#pragma unroll
                for (int r = 0; r < 4; ++r) smax = fmaxf(smax, sfr[qc][kc][r]);
            smax = fmaxf(smax, __shfl_xor(smax, 16));
            smax = fmaxf(smax, __shfl_xor(smax, 32));
            float mn = fmaxf(mrow[qc], smax);
            float alpha = __builtin_amdgcn_exp2f((mrow[qc] - mn) * S2E);
            mrow[qc] = mn;
            float msc = mn * S2E, psum = 0.f;
#pragma unroll
            for (int kc = 0; kc < 4; ++kc)
#pragma unroll
                for (int r = 0; r < 4; ++r) {
                    float p = __builtin_amdgcn_exp2f(sfr[qc][kc][r] * S2E - msc);
                    psum += p;
                    pfv[qc][kc][r] = (_Float16)p;
                }
            psum += __shfl_xor(psum, 16);
            psum += __shfl_xor(psum, 32);
            lrow[qc] = lrow[qc] * alpha + psum;
#pragma unroll
            for (int dc = 0; dc < 4; ++dc) acc[qc][dc] *= alpha;
        }
#pragma unroll
        for (int dc = 0; dc < 4; ++dc) {
            int dd = dc * 16 + lq;
#pragma unroll
            for (int kc = 0; kc < 4; ++kc) {
                half4 vf = *(const half4*)&lds_v[(dd * 64 + kc * 16 + g * 4) ^ ((dd & 15) << 2)];
                acc[0][dc] = __builtin_amdgcn_mfma_f32_16x16x16f16(vf, pfv[0][kc], acc[0][dc], 0, 0, 0);
                acc[1][dc] = __builtin_amdgcn_mfma_f32_16x16x16f16(vf, pfv[1][kc], acc[1][dc], 0, 0, 0);
            }
        }
    }
#pragma unroll
    for (int qc = 0; qc < 2; ++qc) {
        float inv = 1.f / lrow[qc];
        int qrow = q0 + wv * 32 + qc * 16 + lq;
#pragma unroll
        for (int dc = 0; dc < 4; ++dc) {
            f32x4 o = acc[qc][dc] * inv;
            *(f32x4*)(Og + (size_t)qrow * 512 + dc * 16 + g * 4) = o;
        }
    }
}

extern "C" void kernel_launch(void* const* d_in, const int* in_sizes, int n_in,
                              void* d_out, int out_size, void* d_ws, size_t ws_size,
                              hipStream_t stream) {
    const float* Q = (const float*)d_in[0];
    const float* K = (const float*)d_in[1];
    const float* V = (const float*)d_in[2];
    float* O = (float*)d_out;

    const size_t per = (size_t)32 * 2048 * 64;            // elements per tensor
    const size_t need = 2 * per * sizeof(unsigned short); // 16.8 MB (K + V)
    if (ws_size >= need) {
        unsigned short* wsK = (unsigned short*)d_ws;
        unsigned short* wsV = wsK + per;
        cvt_kv_kernel<<<dim3(8192), dim3(256), 0, stream>>>(K, V, wsK, wsV);
        attn_v11_kernel<<<dim3(512), dim3(512), 0, stream>>>(Q, wsK, wsV, O);
    } else {
        attn_v1_kernel<<<dim3(1024), dim3(128), 0, stream>>>(Q, K, V, O);
    }
}

// Round 12
// 59.372 us; speedup vs baseline: 2.7231x; 1.3781x over previous
//
#include <hip/hip_runtime.h>

typedef __attribute__((ext_vector_type(4)))  float    f32x4;
typedef __attribute__((ext_vector_type(16))) float    f32x16;
typedef __attribute__((ext_vector_type(8)))  _Float16 half8;
typedef __attribute__((ext_vector_type(2)))  __fp16   fp16x2;
typedef __attribute__((ext_vector_type(4)))  _Float16 half4;
typedef __attribute__((ext_vector_type(8)))  short    short8;

#define SCL2E 0.18033688011112042f   // (1/8) * log2(e)  — folded into Q

__device__ __forceinline__ unsigned short f2h_bits(float x) {
    union { _Float16 h; unsigned short u; } c;
    c.h = (_Float16)x;
    return c.u;
}

__device__ __forceinline__ void gl_lds16(const unsigned short* g, unsigned short* l) {
    __builtin_amdgcn_global_load_lds((const __attribute__((address_space(1))) void*)g,
                                     (__attribute__((address_space(3))) void*)l, 16, 0, 0);
}

// ============ prepass (fused, UNCHANGED from r11 — verified): K -> granule LDS layout,
//              V -> fragment-major [bh][tile][slot][lane][8] ============
__global__ __launch_bounds__(256)
void cvt_kv_kernel(const float* __restrict__ K, const float* __restrict__ V,
                   unsigned short* __restrict__ wsK, unsigned short* __restrict__ wsV) {
    int bid = blockIdx.x;                           // 0..8191
    if (bid < 4096) {
        // K: [b][kv][h][e] -> granule layout (verified r7)
        int t   = bid * 256 + threadIdx.x;
        int eg  = t & 15;                           // e = eg*4
        int gr  = t >> 4;
        int kv  = gr & 2047, bh = gr >> 11;
        int b = bh >> 3, h = bh & 7;
        const float* sp = K + (((size_t)b * 2048 + kv) * 8 + h) * 64 + eg * 4;
        f32x4 v = *(const f32x4*)sp;
        int T = kv >> 6, R = kv & 31, half = (kv >> 5) & 1;
        int egp = (eg & ~3) | ((eg & 1) << 1) | ((eg >> 1) & 1);   // swap e bits 2,3
        int gnl = (half * 8 + (egp >> 1)) ^ (R & 15);
        size_t idx = (((size_t)bh * 32 + T) * 32 + R) * 128 + gnl * 8 + (egp & 1) * 4;
        union { unsigned short s[4]; unsigned long long u; } o;
        o.s[0] = f2h_bits(v[0]); o.s[1] = f2h_bits(v[1]);
        o.s[2] = f2h_bits(v[2]); o.s[3] = f2h_bits(v[3]);
        *(unsigned long long*)(wsK + idx) = o.u;
    } else {
        // V: fragment-major (verified r9/r11): slot = kh*4 + dh*2 + kc
        int t   = (bid - 4096) * 256 + threadIdx.x;
        int d   = t & 63;
        int g   = t >> 6;
        int kv4 = g & 511, bh = g >> 9;
        int b = bh >> 3, h = bh & 7;
        int kv = kv4 * 4;
        const float* sp = V + (((size_t)b * 2048 + kv) * 8 + h) * 64 + d;
        float v0 = sp[0], v1 = sp[512], v2 = sp[1024], v3 = sp[1536];
        int T    = kv >> 6;
        int kvt  = kv & 63;
        int kh   = kvt >> 5;                 // kv half within tile
        int kvh  = kvt & 31;
        int kc   = kvh >> 4;
        int hi   = (kvh >> 2) & 1;
        int joff = 4 * ((kvh >> 3) & 1);
        int dh   = d >> 5;
        int lane = (d & 31) + 32 * hi;
        size_t idx = (((size_t)bh * 32 + T) * 4096) + ((kh * 4 + dh * 2 + kc) * 64 + lane) * 8 + joff;
        union { unsigned short s[4]; unsigned long long u; } o;
        o.s[0] = f2h_bits(v0); o.s[1] = f2h_bits(v1);
        o.s[2] = f2h_bits(v2); o.s[3] = f2h_bits(v3);
        *(unsigned long long*)(wsV + idx) = o.u;
    }
}

// ---------------- main v12: K via LDS (DMA), V direct-global, spill-safe register budget ----------------
// 8 waves = 4 q-chunks x 2 kv-tile-ranges, QBLK=128, grid 512.
// launch_bounds(512,2): empirical VGPR cap = 128 (r10/r11 post-mortem: arg=4 capped at 64 -> spill).
__global__ __launch_bounds__(512, 2)
void attn_v12_kernel(const float* __restrict__ Q,
                     const unsigned short* __restrict__ wsK,
                     const unsigned short* __restrict__ wsV,
                     float* __restrict__ O) {
    __shared__ __align__(16) unsigned char smem[36864];   // 32KB K-dbuf, reused as 36KB merge
    unsigned short* kl = (unsigned short*)smem;           // [buf][kh][4096]

    const int tid  = threadIdx.x;
    const int lane = tid & 63;
    const int w    = tid >> 6;          // wave 0..7
    const int qw   = w & 3;             // q chunk
    const int kh   = w >> 2;            // kv tile range (0..15 / 16..31)
    const int lq   = lane & 31;
    const int hi   = lane >> 5;

    const int bid = blockIdx.x;
    const int xcd = bid & 7, slot = bid >> 3;
    const int qt  = slot & 15;
    const int bh  = ((slot >> 4) << 3) | xcd;   // XCD-local bh
    const int q0  = qt * 128;
    const int b   = bh >> 3, h = bh & 7;

    const unsigned short* Ksrc = wsK + (size_t)bh * 32 * 4096;   // [tile][32][128]
    const unsigned short* Vsrc = wsV + (size_t)bh * 32 * 4096;   // [tile][slot][lane][8]
    float* Og = O + ((size_t)b * 2048 * 8 + (size_t)h) * 64;

    // ---- Q fragments in registers (v8-verified mapping; scale folded) ----
    half8 qf[4];
    {
        const float* qp = Q + (((size_t)b * 2048 + q0 + qw * 32 + lq) * 8 + h) * 64;
#pragma unroll
        for (int ks = 0; ks < 4; ++ks) {
            f32x4 a = *(const f32x4*)(qp + 16 * ks + 4 * hi);
            f32x4 c = *(const f32x4*)(qp + 16 * ks + 8 + 4 * hi);
            union { fp16x2 h2[4]; half8 v; } u;
            u.h2[0] = __builtin_amdgcn_cvt_pkrtz(a[0] * SCL2E, a[1] * SCL2E);
            u.h2[1] = __builtin_amdgcn_cvt_pkrtz(a[2] * SCL2E, a[3] * SCL2E);
            u.h2[2] = __builtin_amdgcn_cvt_pkrtz(c[0] * SCL2E, c[1] * SCL2E);
            u.h2[3] = __builtin_amdgcn_cvt_pkrtz(c[2] * SCL2E, c[3] * SCL2E);
            qf[ks] = u.v;
        }
    }

    // stage K tiles 0 and 16 into buf 0 (one 16B chunk per thread per tile)
    gl_lds16(Ksrc + (size_t)0  * 4096 + tid * 8, &kl[(0 * 2 + 0) * 4096 + tid * 8]);
    gl_lds16(Ksrc + (size_t)16 * 4096 + tid * 8, &kl[(0 * 2 + 1) * 4096 + tid * 8]);
    __syncthreads();

    // K fragment granule offsets (r7-verified, conflict-free)
    int of0[4], of1[4];
#pragma unroll
    for (int ks = 0; ks < 4; ++ks) {
        of0[ks] = (((ks * 2 + hi)     ^ (lq & 15)) << 3);   // kv rows 0..31 of tile
        of1[ks] = (((8 + ks * 2 + hi) ^ (lq & 15)) << 3);   // kv rows 32..63
    }

    f32x16 acc0 = {0.f,0.f,0.f,0.f,0.f,0.f,0.f,0.f,0.f,0.f,0.f,0.f,0.f,0.f,0.f,0.f};
    f32x16 acc1 = acc0;
    float lrowA = 0.f, lrowB = 0.f;
    const fp16x2 vone = {(__fp16)1.0f, (__fp16)1.0f};

    for (int t = 0; t < 16; ++t) {
        const int cur = t & 1;
        if (t + 1 < 16) {   // stage next K tile pair into other buffer
            const int nxt = cur ^ 1;
            gl_lds16(Ksrc + (size_t)(t + 1)  * 4096 + tid * 8, &kl[(nxt * 2 + 0) * 4096 + tid * 8]);
            gl_lds16(Ksrc + (size_t)(t + 17) * 4096 + tid * 8, &kl[(nxt * 2 + 1) * 4096 + tid * 8]);
        }

        // ---- S^T = K · Q^T from LDS ----
        const unsigned short* kb = &kl[(cur * 2 + kh) * 4096];
        f32x16 s0 = {0.f,0.f,0.f,0.f,0.f,0.f,0.f,0.f,0.f,0.f,0.f,0.f,0.f,0.f,0.f,0.f};
        f32x16 s1 = s0;
        __builtin_amdgcn_s_setprio(1);
#pragma unroll
        for (int ks = 0; ks < 4; ++ks) {
            half8 kf0 = *(const half8*)&kb[lq * 128 + of0[ks]];
            half8 kf1 = *(const half8*)&kb[lq * 128 + of1[ks]];
            s0 = __builtin_amdgcn_mfma_f32_32x32x16_f16(kf0, qf[ks], s0, 0, 0, 0);
            s1 = __builtin_amdgcn_mfma_f32_32x32x16_f16(kf1, qf[ks], s1, 0, 0, 0);
        }
        __builtin_amdgcn_s_setprio(0);

        // ---- V fragments: 8 coalesced global b128, issued here so the softmax
        //      VALU work below covers their L2 latency (short live range -> no spill) ----
        const unsigned short* vp = Vsrc + (size_t)(kh * 16 + t) * 4096;
        half8 vf0 = *(const half8*)&vp[0 * 512 + lane * 8];   // kh0 dh0 kc0
        half8 vf1 = *(const half8*)&vp[1 * 512 + lane * 8];   // kh0 dh0 kc1
        half8 vf2 = *(const half8*)&vp[2 * 512 + lane * 8];   // kh0 dh1 kc0
        half8 vf3 = *(const half8*)&vp[3 * 512 + lane * 8];   // kh0 dh1 kc1
        half8 vf4 = *(const half8*)&vp[4 * 512 + lane * 8];   // kh1 dh0 kc0
        half8 vf5 = *(const half8*)&vp[5 * 512 + lane * 8];   // kh1 dh0 kc1
        half8 vf6 = *(const half8*)&vp[6 * 512 + lane * 8];   // kh1 dh1 kc0
        half8 vf7 = *(const half8*)&vp[7 * 512 + lane * 8];   // kh1 dh1 kc1

        // ---- p = exp2(s); pack to f16; psum via fdot2 (v6-verified) ----
        half8 pf[4];
        float pA = 0.f, pB = 0.f;
#pragma unroll
        for (int hm = 0; hm < 2; ++hm) {
            const f32x16& sb = hm ? s1 : s0;
#pragma unroll
            for (int hk = 0; hk < 2; ++hk) {
                union { fp16x2 h2[4]; half8 v; } u;
#pragma unroll
                for (int j = 0; j < 4; ++j) {
                    float e0 = __builtin_amdgcn_exp2f(sb[8 * hk + 2 * j]);
                    float e1 = __builtin_amdgcn_exp2f(sb[8 * hk + 2 * j + 1]);
                    u.h2[j] = __builtin_amdgcn_cvt_pkrtz(e0, e1);
#if __has_builtin(__builtin_amdgcn_fdot2)
                    if (hm == 0) pA = __builtin_amdgcn_fdot2(u.h2[j], vone, pA, false);
                    else         pB = __builtin_amdgcn_fdot2(u.h2[j], vone, pB, false);
#else
                    if (hm == 0) pA += e0 + e1; else pB += e0 + e1;
#endif
                }
                pf[2 * hm + hk] = u.v;
            }
        }
        lrowA += pA; lrowB += pB;

        // ---- O^T += V^T · P^T  (pf[2*kh+kc] x vf slot kh*4+dh*2+kc; r11-verified pairing) ----
        __builtin_amdgcn_s_setprio(1);
        acc0 = __builtin_amdgcn_mfma_f32_32x32x16_f16(vf0, pf[0], acc0, 0, 0, 0);
        acc1 = __builtin_amdgcn_mfma_f32_32x32x16_f16(vf2, pf[0], acc1, 0, 0, 0);
        acc0 = __builtin_amdgcn_mfma_f32_32x32x16_f16(vf1, pf[1], acc0, 0, 0, 0);
        acc1 = __builtin_amdgcn_mfma_f32_32x32x16_f16(vf3, pf[1], acc1, 0, 0, 0);
        acc0 = __builtin_amdgcn_mfma_f32_32x32x16_f16(vf4, pf[2], acc0, 0, 0, 0);
        acc1 = __builtin_amdgcn_mfma_f32_32x32x16_f16(vf6, pf[2], acc1, 0, 0, 0);
        acc0 = __builtin_amdgcn_mfma_f32_32x32x16_f16(vf5, pf[3], acc0, 0, 0, 0);
        acc1 = __builtin_amdgcn_mfma_f32_32x32x16_f16(vf7, pf[3], acc1, 0, 0, 0);
        __builtin_amdgcn_s_setprio(0);

        __syncthreads();   // K stage(t+1) landed + all LDS reads of cur done
    }

    // ---- epilogue: merge lane halves of l, then merge kh halves via LDS (v6-verified) ----
    float lrow = lrowA + lrowB;
    lrow += __shfl_xor(lrow, 32);

    float* mlds = (float*)smem;   // 4*64*36*4 = 36,864 B
    const int mslot = (qw * 64 + lane) * 36;
    if (kh) {
        float* dst = mlds + mslot;
#pragma unroll
        for (int a = 0; a < 4; ++a) {
            *(f32x4*)(dst + 4 * a)      = (f32x4){acc0[4*a], acc0[4*a+1], acc0[4*a+2], acc0[4*a+3]};
            *(f32x4*)(dst + 16 + 4 * a) = (f32x4){acc1[4*a], acc1[4*a+1], acc1[4*a+2], acc1[4*a+3]};
        }
        dst[32] = lrow;
    }
    __syncthreads();
    if (!kh) {
        const float* src = mlds + mslot;
        float inv = 1.0f / (lrow + src[32]);

        const int qg = q0 + qw * 32 + lq;
        float* orow = Og + (size_t)qg * 512;
#pragma unroll
        for (int a = 0; a < 4; ++a) {
            f32x4 p0 = *(const f32x4*)(src + 4 * a);
            f32x4 p1 = *(const f32x4*)(src + 16 + 4 * a);
            f32x4 o0, o1;
#pragma unroll
            for (int i = 0; i < 4; ++i) {
                o0[i] = (acc0[4 * a + i] + p0[i]) * inv;
                o1[i] = (acc1[4 * a + i] + p1[i]) * inv;
            }
            *(f32x4*)(orow + 8 * a + 4 * hi)      = o0;
            *(f32x4*)(orow + 32 + 8 * a + 4 * hi) = o1;
        }
    }
}

// ================= fallback (round-1 kernel, passes) =================
__device__ __forceinline__ unsigned short f2bf(float f) {
    union { float f; unsigned u; } v; v.f = f;
    unsigned u = v.u;
    u += 0x7fffu + ((u >> 16) & 1u);
    return (unsigned short)(u >> 16);
}

__global__ __launch_bounds__(128, 2)
void attn_v1_kernel(const float* __restrict__ Q, const float* __restrict__ K,
                    const float* __restrict__ V, float* __restrict__ O) {
    __shared__ __align__(16) unsigned short lds_q[64 * 64];
    __shared__ __align__(16) unsigned short lds_k[64 * 64];
    __shared__ __align__(16) unsigned short lds_v[64 * 64];

    const int tid = threadIdx.x, lane = tid & 63, wv = tid >> 6;
    const int lq = lane & 15, g = lane >> 4;
    const int bid = blockIdx.x, xcd = bid & 7, slot = bid >> 3;
    const int qt = slot & 31;
    const int bh = ((slot >> 5) << 3) | xcd;
    const int b = bh >> 3, h = bh & 7;
    const size_t base = ((size_t)b * 2048 * 8 + (size_t)h) * 64;
    const float* Qg = Q + base; const float* Kg = K + base;
    const float* Vg = V + base; float* Og = O + base;
    const int q0 = qt * 64;
    const float S2E = 0.125f * 1.44269504088896341f;

#pragma unroll
    for (int p = 0; p < 16; ++p) {
        int r = (tid >> 5) + p * 4, e = (tid & 31) * 2;
        const float* src = Qg + (size_t)(q0 + r) * 512 + e;
        unsigned pk = (unsigned)f2bf(src[0]) | ((unsigned)f2bf(src[1]) << 16);
        *(unsigned*)&lds_q[(r * 64 + e) ^ ((r & 7) << 3)] = pk;
    }
    __syncthreads();
    short8 qf[2][2];
#pragma unroll
    for (int qc = 0; qc < 2; ++qc) {
        int row = wv * 32 + qc * 16 + lq;
#pragma unroll
        for (int j = 0; j < 2; ++j)
            qf[qc][j] = *(const short8*)&lds_q[(row * 64 + j * 32 + g * 8) ^ ((row & 7) << 3)];
    }
    f32x4 acc[2][4];
#pragma unroll
    for (int qc = 0; qc < 2; ++qc)
#pragma unroll
        for (int dc = 0; dc < 4; ++dc) acc[qc][dc] = (f32x4){0.f, 0.f, 0.f, 0.f};
    float mrow[2] = {-1e30f, -1e30f}, lrow[2] = {0.f, 0.f};

    for (int t = 0; t < 32; ++t) {
        const int kv0 = t * 64;
        __syncthreads();
#pragma unroll
        for (int p = 0; p < 16; ++p) {
            int r = (tid >> 5) + p * 4, e = (tid & 31) * 2;
            const float* src = Kg + (size_t)(kv0 + r) * 512 + e;
            unsigned pk = (unsigned)f2bf(src[0]) | ((unsigned)f2bf(src[1]) << 16);
            *(unsigned*)&lds_k[(r * 64 + e) ^ ((r & 7) << 3)] = pk;
        }
#pragma unroll
        for (int p = 0; p < 16; ++p) {
            int d = tid & 63, kv = (p * 2 + (tid >> 6)) * 2;
            float v0 = Vg[(size_t)(kv0 + kv) * 512 + d];
            float v1 = Vg[(size_t)(kv0 + kv + 1) * 512 + d];
            union { _Float16 hh[2]; unsigned u; } pk;
            pk.hh[0] = (_Float16)v0; pk.hh[1] = (_Float16)v1;
            *(unsigned*)&lds_v[(d * 64 + kv) ^ ((d & 15) << 2)] = pk.u;
        }
        __syncthreads();
        f32x4 sfr[2][4];
#pragma unroll
        for (int kc = 0; kc < 4; ++kc) {
            int row = kc * 16 + lq;
            short8 kf0 = *(const short8*)&lds_k[(row * 64 + 0 + g * 8) ^ ((row & 7) << 3)];
            short8 kf1 = *(const short8*)&lds_k[(row * 64 + 32 + g * 8) ^ ((row & 7) << 3)];
#pragma unroll
            for (int qc = 0; qc < 2; ++qc) {
                f32x4 sx = __builtin_amdgcn_mfma_f32_16x16x32_bf16(kf0, qf[qc][0], (f32x4){0.f,0.f,0.f,0.f}, 0, 0, 0);
                sx = __builtin_amdgcn_mfma_f32_16x16x32_bf16(kf1, qf[qc][1], sx, 0, 0, 0);
                sfr[qc][kc] = sx;
            }
        }
        half4 pfv[2][4];
#pragma unroll
        for (int qc = 0; qc < 2; ++qc) {
            float smax = -1e30f;
#pragma unroll
            for (int kc = 0; kc < 4; ++kc)
#pragma unroll
                for (int r = 0; r < 4; ++r) smax = fmaxf(smax, sfr[qc][kc][r]);
            smax = fmaxf(smax, __shfl_xor(smax, 16));
            smax = fmaxf(smax, __shfl_xor(smax, 32));
            float mn = fmaxf(mrow[qc], smax);
            float alpha = __builtin_amdgcn_exp2f((mrow[qc] - mn) * S2E);
            mrow[qc] = mn;
            float msc = mn * S2E, psum = 0.f;
#pragma unroll
            for (int kc = 0; kc < 4; ++kc)
#pragma unroll
                for (int r = 0; r < 4; ++r) {
                    float p = __builtin_amdgcn_exp2f(sfr[qc][kc][r] * S2E - msc);
                    psum += p;
                    pfv[qc][kc][r] = (_Float16)p;
                }
            psum += __shfl_xor(psum, 16);
            psum += __shfl_xor(psum, 32);
            lrow[qc] = lrow[qc] * alpha + psum;
#pragma unroll
            for (int dc = 0; dc < 4; ++dc) acc[qc][dc] *= alpha;
        }
#pragma unroll
        for (int dc = 0; dc < 4; ++dc) {
            int dd = dc * 16 + lq;
#pragma unroll
            for (int kc = 0; kc < 4; ++kc) {
                half4 vf = *(const half4*)&lds_v[(dd * 64 + kc * 16 + g * 4) ^ ((dd & 15) << 2)];
                acc[0][dc] = __builtin_amdgcn_mfma_f32_16x16x16f16(vf, pfv[0][kc], acc[0][dc], 0, 0, 0);
                acc[1][dc] = __builtin_amdgcn_mfma_f32_16x16x16f16(vf, pfv[1][kc], acc[1][dc], 0, 0, 0);
            }
        }
    }
#pragma unroll
    for (int qc = 0; qc < 2; ++qc) {
        float inv = 1.f / lrow[qc];
        int qrow = q0 + wv * 32 + qc * 16 + lq;
#pragma unroll
        for (int dc = 0; dc < 4; ++dc) {
            f32x4 o = acc[qc][dc] * inv;
            *(f32x4*)(Og + (size_t)qrow * 512 + dc * 16 + g * 4) = o;
        }
    }
}

extern "C" void kernel_launch(void* const* d_in, const int* in_sizes, int n_in,
                              void* d_out, int out_size, void* d_ws, size_t ws_size,
                              hipStream_t stream) {
    const float* Q = (const float*)d_in[0];
    const float* K = (const float*)d_in[1];
    const float* V = (const float*)d_in[2];
    float* O = (float*)d_out;

    const size_t per = (size_t)32 * 2048 * 64;            // elements per tensor
    const size_t need = 2 * per * sizeof(unsigned short); // 16.8 MB (K + V)
    if (ws_size >= need) {
        unsigned short* wsK = (unsigned short*)d_ws;
        unsigned short* wsV = wsK + per;
        cvt_kv_kernel<<<dim3(8192), dim3(256), 0, stream>>>(K, V, wsK, wsV);
        attn_v12_kernel<<<dim3(512), dim3(512), 0, stream>>>(Q, wsK, wsV, O);
    } else {
        attn_v1_kernel<<<dim3(1024), dim3(128), 0, stream>>>(Q, K, V, O);
    }
}